// Round 1
// baseline (512.670 us; speedup 1.0000x reference)
//
#include <hip/hip_runtime.h>

// Starlet 2D: cascaded dilated separable B3 conv, reflect padding.
// Tile 64x64 outputs per 256-thread block; halo = 2*D each side.
#define TX 64
#define TY 64

template<int D>
__global__ __launch_bounds__(256)
void starlet_scale(const float* __restrict__ in, long in_bs,
                   float* __restrict__ det,      long det_bs,
                   float* __restrict__ coa,      long coa_bs)
{
    constexpr int H = 1024, W = 1024;
    constexpr int R  = 2 * D;          // halo
    constexpr int LW = TX + 2 * R;     // lds tile width
    constexpr int LH = TY + 2 * R;     // lds tile height
    constexpr int LS = LW + 1;         // padded stride (bank-conflict break)

    __shared__ float tile[LH * LS];
    __shared__ float htmp[LH * TX];    // horizontal-pass result

    const int tid = threadIdx.x;
    const int bx  = blockIdx.x * TX;
    const int by  = blockIdx.y * TY;
    const int b   = blockIdx.z;

    const float* __restrict__ inp = in + (long)b * in_bs;

    const float k0 = 0.0625f;  // 1/16
    const float k1 = 0.25f;    // 1/4
    const float k2 = 0.375f;   // 3/8

    // Phase 1: cooperative load with reflect boundary (single reflection ok: R<=16 < H)
    for (int i = tid; i < LH * LW; i += 256) {
        int ly = i / LW;
        int lx = i - ly * LW;
        int gy = by - R + ly;
        gy = (gy < 0) ? -gy : ((gy >= H) ? (2 * H - 2 - gy) : gy);
        int gx = bx - R + lx;
        gx = (gx < 0) ? -gx : ((gx >= W) ? (2 * W - 2 - gx) : gx);
        tile[ly * LS + lx] = inp[(long)gy * W + gx];
    }
    __syncthreads();

    // Phase 2: horizontal 5-tap (dilated). htmp[r][x] = sum_j k[j]*tile[r][x + j*D]
    for (int i = tid; i < LH * TX; i += 256) {
        int r = i >> 6;            // TX = 64
        int x = i & (TX - 1);
        const float* t = &tile[r * LS + x];
        htmp[i] = k0 * (t[0] + t[4 * D]) + k1 * (t[D] + t[3 * D]) + k2 * t[2 * D];
    }
    __syncthreads();

    // Phase 3: vertical 5-tap + detail/coarse writes
    for (int i = tid; i < TY * TX; i += 256) {
        int y = i >> 6;
        int x = i & (TX - 1);
        const float* h = &htmp[y * TX + x];
        float conv = k0 * (h[0] + h[4 * D * TX])
                   + k1 * (h[D * TX] + h[3 * D * TX])
                   + k2 * h[2 * D * TX];
        float center = tile[(y + R) * LS + (x + R)];
        long gidx = (long)(by + y) * W + (bx + x);
        det[(long)b * det_bs + gidx] = center - conv;
        coa[(long)b * coa_bs + gidx] = conv;
    }
}

extern "C" void kernel_launch(void* const* d_in, const int* in_sizes, int n_in,
                              void* d_out, int out_size, void* d_ws, size_t ws_size,
                              hipStream_t stream) {
    const float* x = (const float*)d_in[0];
    float* out = (float*)d_out;
    float* ws  = (float*)d_ws;   // needs 16*1024*1024 floats = 64 MiB

    const long HW = 1024L * 1024L;
    const long OB = 5 * HW;      // out per-batch stride (5 channels)

    dim3 grid(1024 / TX, 1024 / TY, 16);
    dim3 block(256);

    // s=0 (d=1): x -> detail ch0, coarse1 -> ws
    starlet_scale<1><<<grid, block, 0, stream>>>(x, HW, out + 0 * HW, OB, ws, HW);
    // s=1 (d=2): ws -> detail ch1, coarse2 -> out ch4 (temp stash)
    starlet_scale<2><<<grid, block, 0, stream>>>(ws, HW, out + 1 * HW, OB, out + 4 * HW, OB);
    // s=2 (d=4): out ch4 -> detail ch2, coarse3 -> ws
    starlet_scale<4><<<grid, block, 0, stream>>>(out + 4 * HW, OB, out + 2 * HW, OB, ws, HW);
    // s=3 (d=8): ws -> detail ch3, coarse4 -> out ch4 (final)
    starlet_scale<8><<<grid, block, 0, stream>>>(ws, HW, out + 3 * HW, OB, out + 4 * HW, OB);
}